// Round 12
// baseline (349.778 us; speedup 1.0000x reference)
//
#include <hip/hip_runtime.h>
#include <hip/hip_bf16.h>
#include <hip/hip_fp16.h>

// GCN: h1 = relu(gcn(x, W1, b1)); h2 = relu(gcn(h1, W2, b2)); out = h2@Wl + bl
// gcn(x,W,b) = D^-1/2 (A+I) D^-1/2 (xW) + b, deg = in-degree(dst)+1
// Pipeline: single-pass bucket scatter (LDS counting sort, global atomic
// space reservation into fixed-CAP bucket regions) -> per-bucket LDS
// finisher (folds bucket-base scan) -> mfma GEMM1 -> 2x fused gather+GEMM.
// Fused kernel: 4KB LDS, W frags from global (L2-hot), 4-deep gather unroll
// (proven best: occupancy 81% beats deeper unroll at 51%).

#define FEAT 128
#define EPB 4096       // edges per scatter chunk
#define NPB_SHIFT 9    // 512 nodes per bucket
#define NPB (1 << NPB_SHIFT)
#define CAP 20480      // per-bucket ebuf capacity (mean 16384 + 32 sigma)

typedef unsigned short u16;
typedef unsigned int u32;
typedef _Float16 f16;
typedef __attribute__((ext_vector_type(8))) _Float16 f16x8;
typedef __attribute__((ext_vector_type(4))) float f32x4;

static __device__ __forceinline__ u16 f2h(float f) {
    f16 h = (f16)f;
    return *reinterpret_cast<u16*>(&h);
}

// ---------- single-pass scatter: LDS hist + global reservation + counting sort ----------
__global__ __launch_bounds__(256) void scatter_kernel(const int* __restrict__ src,
                                                      const int* __restrict__ dst,
                                                      int* __restrict__ bcount,
                                                      u32* __restrict__ ebuf,
                                                      long long E, int nbuck) {
    __shared__ int hist[256];
    __shared__ int gb[256];     // reserved base within bucket region
    __shared__ int lbase[256];  // local exclusive scan
    __shared__ int lofs[256];
    __shared__ u16 bslot[EPB];
    __shared__ u32 sorted[EPB];
    const int blk = blockIdx.x;
    const int tid = threadIdx.x;
    long long e0 = (long long)blk * EPB;
    if (e0 >= E) return;
    const int cnt = (int)((E - e0 < EPB) ? (E - e0) : EPB);

    hist[tid] = 0;
    __syncthreads();
    for (int i = tid; i < cnt; i += 256)
        atomicAdd(&hist[dst[e0 + i] >> NPB_SHIFT], 1);
    __syncthreads();

    const int h = hist[tid];
    if (tid < nbuck && h > 0) gb[tid] = atomicAdd(&bcount[tid], h);
    lbase[tid] = h;
    lofs[tid] = h;
    __syncthreads();
    for (int off = 1; off < 256; off <<= 1) {
        int a = (tid >= off) ? lbase[tid - off] : 0;
        __syncthreads();
        lbase[tid] += a;
        __syncthreads();
    }
    int excl = lbase[tid] - lofs[tid];
    __syncthreads();
    lbase[tid] = excl;
    lofs[tid] = excl;
    __syncthreads();

    // stage bucket-sorted edges in LDS (dst/src re-read: L1/L2-hot)
    for (int i = tid; i < cnt; i += 256) {
        int d = dst[e0 + i];
        int b = d >> NPB_SHIFT;
        int p = atomicAdd(&lofs[b], 1);
        sorted[p] = ((u32)src[e0 + i] << NPB_SHIFT) | (u32)(d & (NPB - 1));
        bslot[p] = (u16)b;
    }
    __syncthreads();

    // coalesced write-out into fixed-capacity bucket regions
    for (int i = tid; i < cnt; i += 256) {
        int b = bslot[i];
        int pos = gb[b] + (i - lbase[b]);
        if (pos < CAP) ebuf[(size_t)b * CAP + pos] = sorted[i];
    }
}

// ---------- per-bucket finisher: bucket-base scan + hist + scan + row_ptr/dinv + col ----------
__global__ __launch_bounds__(1024) void bucket_finish_kernel(const u32* __restrict__ ebuf,
                                                             const int* __restrict__ bcount,
                                                             int* __restrict__ col,
                                                             int* __restrict__ row_ptr,
                                                             float* __restrict__ dinv,
                                                             int N, int nbuck, long long E) {
    __shared__ int hist[NPB];
    __shared__ int scn[NPB];
    __shared__ int cb[256];
    const int tid = threadIdx.x;
    const int b = blockIdx.x;
    const int base = b << NPB_SHIFT;

    // inclusive scan of bcount -> cb (dense col base = cb[b] - bcount[b])
    if (tid < 256) cb[tid] = (tid < nbuck) ? bcount[tid] : 0;
    __syncthreads();
    for (int off = 1; off < 256; off <<= 1) {
        int a = 0;
        if (tid < 256 && tid >= off) a = cb[tid - off];
        __syncthreads();
        if (tid < 256) cb[tid] += a;
        __syncthreads();
    }
    const int tot = bcount[b];
    const int colBase = cb[b] - tot;
    const size_t e0 = (size_t)b * CAP;

    if (tid < NPB) hist[tid] = 0;
    __syncthreads();
    for (int e = tid; e < tot; e += 1024)
        atomicAdd(&hist[ebuf[e0 + e] & (NPB - 1)], 1);
    __syncthreads();

    if (tid < NPB) scn[tid] = hist[tid];
    __syncthreads();
    for (int off = 1; off < NPB; off <<= 1) {
        int a = 0;
        if (tid < NPB && tid >= off) a = scn[tid - off];
        __syncthreads();
        if (tid < NPB && tid >= off) scn[tid] += a;
        __syncthreads();
    }

    int lim = N - base; if (lim > NPB) lim = NPB;
    if (tid < lim) {
        int h = hist[tid];
        int excl = scn[tid] - h;
        row_ptr[base + tid] = colBase + excl;
        dinv[base + tid] = rsqrtf((float)(h + 1));
    }
    if (b == nbuck - 1 && tid == 0) row_ptr[N] = (int)E;
    __syncthreads();

    if (tid < NPB) hist[tid] = colBase + (scn[tid] - hist[tid]);
    __syncthreads();
    for (int e = tid; e < tot; e += 1024) {
        u32 sd = ebuf[e0 + e];
        int p = atomicAdd(&hist[sd & (NPB - 1)], 1);
        col[p] = (int)(sd >> NPB_SHIFT);
    }
}

// ---------- prepack W (128x128 f32, row-major k x n) into MFMA B-frag order ----------
__global__ __launch_bounds__(256) void prepack_w_kernel(const float* __restrict__ Wa,
                                                        const float* __restrict__ Wb,
                                                        const float* __restrict__ Wc,
                                                        u16* __restrict__ Wfa,
                                                        u16* __restrict__ Wfb,
                                                        u16* __restrict__ Wfc) {
    const float* W = (blockIdx.x == 0) ? Wa : (blockIdx.x == 1) ? Wb : Wc;
    u16* Wf = (blockIdx.x == 0) ? Wfa : (blockIdx.x == 1) ? Wfb : Wfc;
    for (int i = threadIdx.x; i < 16384; i += 256) {
        int j = i & 7;
        int lane = (i >> 3) & 63;
        int nb = (i >> 9) & 7;
        int kk = i >> 12;
        int k = kk * 32 + (lane >> 4) * 8 + j;
        int n = nb * 16 + (lane & 15);
        Wf[i] = f2h(W[k * 128 + n]);
    }
}

// ---------- layer-1 GEMM: P1' = dinv * (x @ W1), fp32 x converted in-register ----------
__global__ __launch_bounds__(256) void mfma_gemm1_kernel(const float* __restrict__ Af,
                                                         const u16* __restrict__ Wf,
                                                         const float* __restrict__ scale,
                                                         u16* __restrict__ Yh, int M) {
    __shared__ u16 sB[16384];  // 32 KB
    for (int i = threadIdx.x; i < 2048; i += 256)
        ((uint4*)sB)[i] = ((const uint4*)Wf)[i];
    __syncthreads();

    const int wid = threadIdx.x >> 6;
    const int lane = threadIdx.x & 63;
    const int lrow = lane & 15;
    const int lkb = lane >> 4;

    const int nstrip = (M + 31) / 32;
    for (int strip = blockIdx.x * 4 + wid; strip < nstrip; strip += gridDim.x * 4) {
        const int row0 = strip * 32;
        f16x8 a[2][4];
#pragma unroll
        for (int t = 0; t < 2; ++t)
#pragma unroll
            for (int kk = 0; kk < 4; ++kk) {
                const float4* p = (const float4*)&Af[(size_t)(row0 + t * 16 + lrow) * FEAT +
                                                     kk * 32 + lkb * 8];
                float4 u0 = p[0], u1 = p[1];
                f16x8 av;
                av[0] = (f16)u0.x; av[1] = (f16)u0.y; av[2] = (f16)u0.z; av[3] = (f16)u0.w;
                av[4] = (f16)u1.x; av[5] = (f16)u1.y; av[6] = (f16)u1.z; av[7] = (f16)u1.w;
                a[t][kk] = av;
            }
        f32x4 acc[2][8];
#pragma unroll
        for (int t = 0; t < 2; ++t)
#pragma unroll
            for (int nb = 0; nb < 8; ++nb) {
                acc[t][nb][0] = 0.f; acc[t][nb][1] = 0.f;
                acc[t][nb][2] = 0.f; acc[t][nb][3] = 0.f;
            }
#pragma unroll
        for (int kk = 0; kk < 4; ++kk)
#pragma unroll
            for (int nb = 0; nb < 8; ++nb) {
                f16x8 b = *(const f16x8*)&sB[((kk * 8 + nb) * 64 + lane) * 8];
                acc[0][nb] = __builtin_amdgcn_mfma_f32_16x16x32_f16(a[0][kk], b, acc[0][nb], 0, 0, 0);
                acc[1][nb] = __builtin_amdgcn_mfma_f32_16x16x32_f16(a[1][kk], b, acc[1][nb], 0, 0, 0);
            }
#pragma unroll
        for (int t = 0; t < 2; ++t)
#pragma unroll
            for (int nb = 0; nb < 8; ++nb)
#pragma unroll
                for (int r = 0; r < 4; ++r) {
                    int row = row0 + t * 16 + (lane >> 4) * 4 + r;
                    int c = nb * 16 + (lane & 15);
                    Yh[(size_t)row * FEAT + c] = f2h(acc[t][nb][r] * scale[row]);
                }
    }
}

// ---------- fused gather + next-layer GEMM (4 KB LDS; W frags from global) ----------
__global__ __launch_bounds__(256) void gather_gemm_kernel(const int* __restrict__ row_ptr,
                                                          const int* __restrict__ col,
                                                          const float* __restrict__ dinv,
                                                          const u16* __restrict__ Pin,
                                                          const float* __restrict__ aggBias,
                                                          const u16* __restrict__ Wf,
                                                          const float* __restrict__ headBias,
                                                          u16* __restrict__ Yh,
                                                          float* __restrict__ Yf, int N) {
    __shared__ u16 tile[16 * 128];  // 4 KB; XOR-swizzled rows

    const int lane16 = threadIdx.x & 15;
    const int grp = threadIdx.x >> 4;  // 0..15
    const int row0 = blockIdx.x * 16;
    const int n = row0 + grp;
    const int f8 = lane16 * 8;

    float a0 = 0.f, a1 = 0.f, a2 = 0.f, a3 = 0.f;
    float a4 = 0.f, a5 = 0.f, a6 = 0.f, a7 = 0.f;

    if (n < N) {
        const float di = dinv[n];
        {
            uint4 sv = *(const uint4*)&Pin[(size_t)n * FEAT + f8];
            float2 f0 = __half22float2(*(__half2*)&sv.x);
            float2 f1 = __half22float2(*(__half2*)&sv.y);
            float2 f2 = __half22float2(*(__half2*)&sv.z);
            float2 f3 = __half22float2(*(__half2*)&sv.w);
            a0 = f0.x; a1 = f0.y; a2 = f1.x; a3 = f1.y;
            a4 = f2.x; a5 = f2.y; a6 = f3.x; a7 = f3.y;
        }
#define ACC8(v) { \
        float2 f0 = __half22float2(*(__half2*)&(v).x); \
        float2 f1 = __half22float2(*(__half2*)&(v).y); \
        float2 f2 = __half22float2(*(__half2*)&(v).z); \
        float2 f3 = __half22float2(*(__half2*)&(v).w); \
        a0 += f0.x; a1 += f0.y; a2 += f1.x; a3 += f1.y; \
        a4 += f2.x; a5 += f2.y; a6 += f3.x; a7 += f3.y; }
        const int start = row_ptr[n];
        const int end = row_ptr[n + 1];
        for (int e0 = start; e0 < end; e0 += 16) {
            int mye = e0 + lane16;
            int s = (mye < end) ? col[mye] : -1;
            int jmax = end - e0; if (jmax > 16) jmax = 16;
            int j = 0;
            for (; j + 3 < jmax; j += 4) {
                int s0 = __shfl(s, j, 16),     s1 = __shfl(s, j + 1, 16);
                int s2 = __shfl(s, j + 2, 16), s3 = __shfl(s, j + 3, 16);
                uint4 v0 = *(const uint4*)&Pin[(size_t)s0 * FEAT + f8];
                uint4 v1 = *(const uint4*)&Pin[(size_t)s1 * FEAT + f8];
                uint4 v2 = *(const uint4*)&Pin[(size_t)s2 * FEAT + f8];
                uint4 v3 = *(const uint4*)&Pin[(size_t)s3 * FEAT + f8];
                ACC8(v0); ACC8(v1); ACC8(v2); ACC8(v3);
            }
            for (; j < jmax; ++j) {
                int s0 = __shfl(s, j, 16);
                uint4 v0 = *(const uint4*)&Pin[(size_t)s0 * FEAT + f8];
                ACC8(v0);
            }
        }
#undef ACC8
        const float4 b0 = *(const float4*)&aggBias[f8];
        const float4 b1 = *(const float4*)&aggBias[f8 + 4];
        a0 = fmaxf(a0 * di + b0.x, 0.f); a1 = fmaxf(a1 * di + b0.y, 0.f);
        a2 = fmaxf(a2 * di + b0.z, 0.f); a3 = fmaxf(a3 * di + b0.w, 0.f);
        a4 = fmaxf(a4 * di + b1.x, 0.f); a5 = fmaxf(a5 * di + b1.y, 0.f);
        a6 = fmaxf(a6 * di + b1.z, 0.f); a7 = fmaxf(a7 * di + b1.w, 0.f);
    }

    // write h row into swizzled LDS tile (zeros for n >= N)
    {
        f16x8 hv;
        hv[0] = (f16)a0; hv[1] = (f16)a1; hv[2] = (f16)a2; hv[3] = (f16)a3;
        hv[4] = (f16)a4; hv[5] = (f16)a5; hv[6] = (f16)a6; hv[7] = (f16)a7;
        *(f16x8*)&tile[grp * 128 + ((lane16 * 8) ^ ((grp & 15) << 3))] = hv;
    }
    __syncthreads();

    // Phase 2: 4 waves x 2 n-blocks; A-frags from swizzled tile, B-frags from global
    const int lane = threadIdx.x & 63;
    const int wid = threadIdx.x >> 6;
    const int trow = lane & 15;
    f16x8 af[4];
#pragma unroll
    for (int kk = 0; kk < 4; ++kk)
        af[kk] = *(const f16x8*)&tile[trow * 128 +
                                      ((kk * 32 + (lane >> 4) * 8) ^ ((trow & 15) << 3))];
#pragma unroll
    for (int nb2 = 0; nb2 < 2; ++nb2) {
        const int nb = wid * 2 + nb2;
        f32x4 acc;
        acc[0] = 0.f; acc[1] = 0.f; acc[2] = 0.f; acc[3] = 0.f;
#pragma unroll
        for (int kk = 0; kk < 4; ++kk) {
            f16x8 b = *(const f16x8*)&Wf[((kk * 8 + nb) * 64 + lane) * 8];
            acc = __builtin_amdgcn_mfma_f32_16x16x32_f16(af[kk], b, acc, 0, 0, 0);
        }
        const int c = nb * 16 + (lane & 15);
#pragma unroll
        for (int r = 0; r < 4; ++r) {
            int row = row0 + (lane >> 4) * 4 + r;
            if (row < N) {
                float v = acc[r];
                if (Yh) {
                    Yh[(size_t)row * FEAT + c] = f2h(v * dinv[row]);
                } else {
                    Yf[(size_t)row * FEAT + c] = v + headBias[c];
                }
            }
        }
    }
}

extern "C" void kernel_launch(void* const* d_in, const int* in_sizes, int n_in,
                              void* d_out, int out_size, void* d_ws, size_t ws_size,
                              hipStream_t stream) {
    const float* x  = (const float*)d_in[0];
    const int*   ei = (const int*)d_in[1];
    const float* W1 = (const float*)d_in[2];
    const float* b1 = (const float*)d_in[3];
    const float* W2 = (const float*)d_in[4];
    const float* b2 = (const float*)d_in[5];
    const float* Wl = (const float*)d_in[6];
    const float* bl = (const float*)d_in[7];
    float* out = (float*)d_out;

    const int N = in_sizes[0] / FEAT;      // 100000
    const long long E = in_sizes[1] / 2;   // 3200000
    const int* src = ei;
    const int* dst = ei + E;

    const int nbuck = (N + NPB - 1) >> NPB_SHIFT;    // 196
    const int nchunks = (int)((E + EPB - 1) / EPB);  // 782

    // workspace layout (~68 MB); ebuf (196*CAP u32 = 16.1MB) aliases PbA
    u16*   PbA     = (u16*)d_ws;                       // N*128 fp16
    u16*   PbB     = PbA + (long long)N * FEAT;        // N*128 fp16
    float* dinv    = (float*)(PbB + (long long)N * FEAT);
    int*   row_ptr = (int*)(dinv + N);                 // N+1
    int*   bcount  = row_ptr + N + 1;                  // 256
    u16*   Wf1     = (u16*)(bcount + 256);             // 16384
    u16*   Wf2     = Wf1 + 16384;
    u16*   Wfl     = Wf2 + 16384;
    int*   col     = (int*)(Wfl + 16384);              // E
    u32*   ebuf    = (u32*)PbA;                        // 196*CAP u32

    // ---- CSR build: single-pass scatter + finisher ----
    hipMemsetAsync(bcount, 0, 256 * sizeof(int), stream);
    scatter_kernel<<<nchunks, 256, 0, stream>>>(src, dst, bcount, ebuf, E, nbuck);
    bucket_finish_kernel<<<nbuck, 1024, 0, stream>>>(ebuf, bcount, col, row_ptr,
                                                     dinv, N, nbuck, E);

    // ---- weight prepack ----
    prepack_w_kernel<<<3, 256, 0, stream>>>(W1, W2, Wl, Wf1, Wf2, Wfl);

    const int gemmGrid = ((N + 31) / 32 + 3) / 4;
    const int fusedGrid = (N + 15) / 16;

    // ---- layer 1 projection: P1' = dinv * (x @ W1) (writes PbA; ebuf consumed) ----
    mfma_gemm1_kernel<<<gemmGrid, 256, 0, stream>>>(x, Wf1, dinv, PbA, N);

    // ---- h1 agg + layer-2 projection: P2' = dinv * (relu(agg)@W2) ----
    gather_gemm_kernel<<<fusedGrid, 256, 0, stream>>>(row_ptr, col, dinv, PbA, b1,
                                                      Wf2, nullptr, PbB, nullptr, N);

    // ---- h2 agg + head: out = relu(agg) @ Wl + bl ----
    gather_gemm_kernel<<<fusedGrid, 256, 0, stream>>>(row_ptr, col, dinv, PbB, b2,
                                                      Wfl, bl, nullptr, out, N);
}

// Round 13
// 331.071 us; speedup vs baseline: 1.0565x; 1.0565x over previous
//
#include <hip/hip_runtime.h>
#include <hip/hip_bf16.h>
#include <hip/hip_fp16.h>

// GCN: h1 = relu(gcn(x, W1, b1)); h2 = relu(gcn(h1, W2, b2)); out = h2@Wl + bl
// gcn(x,W,b) = D^-1/2 (A+I) D^-1/2 (xW) + b, deg = in-degree(dst)+1
// Pipeline: CSR build (bucket radix by dst>>9, packed u32 ebuf, LDS finisher)
//   -> mfma_gemm1: P1' = dinv * (x @ W1)            (fp32 x in-reg converted)
//   -> gather+GEMM fused: h1 = relu(dinv*agg(P1')+b1); P2' = dinv*(h1@W2)
//   -> gather+GEMM fused: h2 = relu(dinv*agg(P2')+b2); out = h2@Wl + bl
// Fused kernel: 4KB LDS (h-tile only), W frags direct from global (L2-hot),
// 4-deep gather unroll. [R11: 8-deep unroll -> VGPR 48, occ 51%, SLOWER.
//  R12: single-pass scatter front-end -> +19us, SLOWER. This config = best.]

#define FEAT 128
#define EPB 4096       // edges per radix chunk
#define NPB_SHIFT 9    // 512 nodes per bucket
#define NPB (1 << NPB_SHIFT)

typedef unsigned short u16;
typedef unsigned int u32;
typedef _Float16 f16;
typedef __attribute__((ext_vector_type(8))) _Float16 f16x8;
typedef __attribute__((ext_vector_type(4))) float f32x4;

static __device__ __forceinline__ u16 f2h(float f) {
    f16 h = (f16)f;
    return *reinterpret_cast<u16*>(&h);
}

// ---------- bucket radix: count per (bucket, chunk) ----------
__global__ __launch_bounds__(256) void radix_count_kernel(const int* __restrict__ dst,
                                                          int* __restrict__ cmat,
                                                          long long E, int nbuck, int nblk) {
    __shared__ int h[256];
    int blk = blockIdx.x;
    for (int i = threadIdx.x; i < nbuck; i += 256) h[i] = 0;
    __syncthreads();
    long long e0 = (long long)blk * EPB;
    long long eend = e0 + EPB; if (eend > E) eend = E;
    for (long long e = e0 + threadIdx.x; e < eend; e += 256)
        atomicAdd(&h[dst[e] >> NPB_SHIFT], 1);
    __syncthreads();
    for (int i = threadIdx.x; i < nbuck; i += 256)
        cmat[(long long)i * nblk + blk] = h[i];
}

__global__ __launch_bounds__(256) void radix_btot_kernel(const int* __restrict__ cmat,
                                                         int* __restrict__ btot, int nblk) {
    __shared__ int tmp[256];
    long long row = (long long)blockIdx.x * nblk;
    int s = 0;
    for (int i = threadIdx.x; i < nblk; i += 256) s += cmat[row + i];
    tmp[threadIdx.x] = s;
    __syncthreads();
    for (int off = 128; off > 0; off >>= 1) {
        if (threadIdx.x < off) tmp[threadIdx.x] += tmp[threadIdx.x + off];
        __syncthreads();
    }
    if (threadIdx.x == 0) btot[blockIdx.x] = tmp[0];
}

__global__ __launch_bounds__(256) void radix_bscan_kernel(const int* __restrict__ btot,
                                                          int* __restrict__ bbase, int nbuck) {
    __shared__ int tmp[256];
    int t = threadIdx.x;
    int v = (t < nbuck) ? btot[t] : 0;
    tmp[t] = v;
    __syncthreads();
    for (int off = 1; off < 256; off <<= 1) {
        int a = (t >= off) ? tmp[t - off] : 0;
        __syncthreads();
        tmp[t] += a;
        __syncthreads();
    }
    if (t < nbuck) bbase[t] = tmp[t] - v;
}

__global__ __launch_bounds__(256) void radix_colscan_kernel(int* __restrict__ cmat,
                                                            const int* __restrict__ bbase,
                                                            int nblk) {
    __shared__ int tmp[256];
    __shared__ int carry;
    long long row = (long long)blockIdx.x * nblk;
    if (threadIdx.x == 0) carry = bbase[blockIdx.x];
    __syncthreads();
    for (int c0 = 0; c0 < nblk; c0 += 256) {
        int i = c0 + threadIdx.x;
        int v = (i < nblk) ? cmat[row + i] : 0;
        tmp[threadIdx.x] = v;
        __syncthreads();
        for (int off = 1; off < 256; off <<= 1) {
            int a = (threadIdx.x >= off) ? tmp[threadIdx.x - off] : 0;
            __syncthreads();
            tmp[threadIdx.x] += a;
            __syncthreads();
        }
        if (i < nblk) cmat[row + i] = tmp[threadIdx.x] - v + carry;
        __syncthreads();
        if (threadIdx.x == 0) carry += tmp[255];
        __syncthreads();
    }
}

// ---------- scatter: block-local LDS counting sort -> coalesced packed writes ----------
__global__ __launch_bounds__(256) void radix_scatter_kernel(const int* __restrict__ src,
                                                            const int* __restrict__ dst,
                                                            const int* __restrict__ cmat,
                                                            u32* __restrict__ ebuf,
                                                            long long E, int nbuck, int nblk) {
    __shared__ int gbase[256];
    __shared__ int lbase[256];
    __shared__ int lofs[256];
    __shared__ u16 bslot[EPB];
    __shared__ u32 sorted[EPB];
    const int blk = blockIdx.x;
    const int tid = threadIdx.x;
    long long e0 = (long long)blk * EPB;
    if (e0 >= E) return;
    const int cnt = (int)((E - e0 < EPB) ? (E - e0) : EPB);

    int v = 0;
    if (tid < nbuck) {
        int base = cmat[(long long)tid * nblk + blk];
        int nxt;
        if (blk + 1 < nblk) nxt = cmat[(long long)tid * nblk + blk + 1];
        else nxt = (tid + 1 < nbuck) ? cmat[(long long)(tid + 1) * nblk] : (int)E;
        gbase[tid] = base;
        v = nxt - base;
    }
    lbase[tid] = v;
    lofs[tid] = v;
    __syncthreads();
    for (int off = 1; off < 256; off <<= 1) {
        int a = (tid >= off) ? lbase[tid - off] : 0;
        __syncthreads();
        lbase[tid] += a;
        __syncthreads();
    }
    int excl = lbase[tid] - lofs[tid];
    __syncthreads();
    lbase[tid] = excl;
    lofs[tid] = excl;
    __syncthreads();

    for (int i = tid; i < cnt; i += 256) {
        int d = dst[e0 + i];
        int b = d >> NPB_SHIFT;
        int p = atomicAdd(&lofs[b], 1);
        sorted[p] = ((u32)src[e0 + i] << NPB_SHIFT) | (u32)(d & (NPB - 1));
        bslot[p] = (u16)b;
    }
    __syncthreads();

    for (int i = tid; i < cnt; i += 256) {
        int b = bslot[i];
        ebuf[gbase[b] + (i - lbase[b])] = sorted[i];
    }
}

// ---------- per-bucket finisher: hist + scan + row_ptr/dinv + col fill ----------
__global__ __launch_bounds__(1024) void bucket_finish_kernel(const u32* __restrict__ ebuf,
                                                             const int* __restrict__ bbase,
                                                             const int* __restrict__ btot,
                                                             int* __restrict__ col,
                                                             int* __restrict__ row_ptr,
                                                             float* __restrict__ dinv,
                                                             int N, int nbuck, long long E) {
    __shared__ int hist[NPB];
    __shared__ int scn[NPB];
    const int tid = threadIdx.x;
    const int b = blockIdx.x;
    const int e0 = bbase[b];
    const int tot = btot[b];
    const int base = b << NPB_SHIFT;

    if (tid < NPB) hist[tid] = 0;
    __syncthreads();
    for (int e = e0 + tid; e < e0 + tot; e += 1024)
        atomicAdd(&hist[ebuf[e] & (NPB - 1)], 1);
    __syncthreads();

    if (tid < NPB) scn[tid] = hist[tid];
    __syncthreads();
    for (int off = 1; off < NPB; off <<= 1) {
        int a = 0;
        if (tid < NPB && tid >= off) a = scn[tid - off];
        __syncthreads();
        if (tid < NPB && tid >= off) scn[tid] += a;
        __syncthreads();
    }

    int lim = N - base; if (lim > NPB) lim = NPB;
    if (tid < lim) {
        int h = hist[tid];
        int excl = scn[tid] - h;
        row_ptr[base + tid] = e0 + excl;
        dinv[base + tid] = rsqrtf((float)(h + 1));
    }
    if (b == nbuck - 1 && tid == 0) row_ptr[N] = (int)E;
    __syncthreads();

    if (tid < NPB) hist[tid] = e0 + (scn[tid] - hist[tid]);
    __syncthreads();
    for (int e = e0 + tid; e < e0 + tot; e += 1024) {
        u32 sd = ebuf[e];
        int p = atomicAdd(&hist[sd & (NPB - 1)], 1);
        col[p] = (int)(sd >> NPB_SHIFT);
    }
}

// ---------- prepack W (128x128 f32, row-major k x n) into MFMA B-frag order ----------
__global__ __launch_bounds__(256) void prepack_w_kernel(const float* __restrict__ Wa,
                                                        const float* __restrict__ Wb,
                                                        const float* __restrict__ Wc,
                                                        u16* __restrict__ Wfa,
                                                        u16* __restrict__ Wfb,
                                                        u16* __restrict__ Wfc) {
    const float* W = (blockIdx.x == 0) ? Wa : (blockIdx.x == 1) ? Wb : Wc;
    u16* Wf = (blockIdx.x == 0) ? Wfa : (blockIdx.x == 1) ? Wfb : Wfc;
    for (int i = threadIdx.x; i < 16384; i += 256) {
        int j = i & 7;
        int lane = (i >> 3) & 63;
        int nb = (i >> 9) & 7;
        int kk = i >> 12;
        int k = kk * 32 + (lane >> 4) * 8 + j;
        int n = nb * 16 + (lane & 15);
        Wf[i] = f2h(W[k * 128 + n]);
    }
}

// ---------- layer-1 GEMM: P1' = dinv * (x @ W1), fp32 x converted in-register ----------
__global__ __launch_bounds__(256) void mfma_gemm1_kernel(const float* __restrict__ Af,
                                                         const u16* __restrict__ Wf,
                                                         const float* __restrict__ scale,
                                                         u16* __restrict__ Yh, int M) {
    __shared__ u16 sB[16384];  // 32 KB
    for (int i = threadIdx.x; i < 2048; i += 256)
        ((uint4*)sB)[i] = ((const uint4*)Wf)[i];
    __syncthreads();

    const int wid = threadIdx.x >> 6;
    const int lane = threadIdx.x & 63;
    const int lrow = lane & 15;
    const int lkb = lane >> 4;

    const int nstrip = (M + 31) / 32;
    for (int strip = blockIdx.x * 4 + wid; strip < nstrip; strip += gridDim.x * 4) {
        const int row0 = strip * 32;
        f16x8 a[2][4];
#pragma unroll
        for (int t = 0; t < 2; ++t)
#pragma unroll
            for (int kk = 0; kk < 4; ++kk) {
                const float4* p = (const float4*)&Af[(size_t)(row0 + t * 16 + lrow) * FEAT +
                                                     kk * 32 + lkb * 8];
                float4 u0 = p[0], u1 = p[1];
                f16x8 av;
                av[0] = (f16)u0.x; av[1] = (f16)u0.y; av[2] = (f16)u0.z; av[3] = (f16)u0.w;
                av[4] = (f16)u1.x; av[5] = (f16)u1.y; av[6] = (f16)u1.z; av[7] = (f16)u1.w;
                a[t][kk] = av;
            }
        f32x4 acc[2][8];
#pragma unroll
        for (int t = 0; t < 2; ++t)
#pragma unroll
            for (int nb = 0; nb < 8; ++nb) {
                acc[t][nb][0] = 0.f; acc[t][nb][1] = 0.f;
                acc[t][nb][2] = 0.f; acc[t][nb][3] = 0.f;
            }
#pragma unroll
        for (int kk = 0; kk < 4; ++kk)
#pragma unroll
            for (int nb = 0; nb < 8; ++nb) {
                f16x8 b = *(const f16x8*)&sB[((kk * 8 + nb) * 64 + lane) * 8];
                acc[0][nb] = __builtin_amdgcn_mfma_f32_16x16x32_f16(a[0][kk], b, acc[0][nb], 0, 0, 0);
                acc[1][nb] = __builtin_amdgcn_mfma_f32_16x16x32_f16(a[1][kk], b, acc[1][nb], 0, 0, 0);
            }
#pragma unroll
        for (int t = 0; t < 2; ++t)
#pragma unroll
            for (int nb = 0; nb < 8; ++nb)
#pragma unroll
                for (int r = 0; r < 4; ++r) {
                    int row = row0 + t * 16 + (lane >> 4) * 4 + r;
                    int c = nb * 16 + (lane & 15);
                    Yh[(size_t)row * FEAT + c] = f2h(acc[t][nb][r] * scale[row]);
                }
    }
}

// ---------- fused gather + next-layer GEMM (4 KB LDS; W frags from global) ----------
__global__ __launch_bounds__(256) void gather_gemm_kernel(const int* __restrict__ row_ptr,
                                                          const int* __restrict__ col,
                                                          const float* __restrict__ dinv,
                                                          const u16* __restrict__ Pin,
                                                          const float* __restrict__ aggBias,
                                                          const u16* __restrict__ Wf,
                                                          const float* __restrict__ headBias,
                                                          u16* __restrict__ Yh,
                                                          float* __restrict__ Yf, int N) {
    __shared__ u16 tile[16 * 128];  // 4 KB; XOR-swizzled rows

    const int lane16 = threadIdx.x & 15;
    const int grp = threadIdx.x >> 4;  // 0..15
    const int row0 = blockIdx.x * 16;
    const int n = row0 + grp;
    const int f8 = lane16 * 8;

    float a0 = 0.f, a1 = 0.f, a2 = 0.f, a3 = 0.f;
    float a4 = 0.f, a5 = 0.f, a6 = 0.f, a7 = 0.f;

    if (n < N) {
        const float di = dinv[n];
        {
            uint4 sv = *(const uint4*)&Pin[(size_t)n * FEAT + f8];
            float2 f0 = __half22float2(*(__half2*)&sv.x);
            float2 f1 = __half22float2(*(__half2*)&sv.y);
            float2 f2 = __half22float2(*(__half2*)&sv.z);
            float2 f3 = __half22float2(*(__half2*)&sv.w);
            a0 = f0.x; a1 = f0.y; a2 = f1.x; a3 = f1.y;
            a4 = f2.x; a5 = f2.y; a6 = f3.x; a7 = f3.y;
        }
#define ACC8(v) { \
        float2 f0 = __half22float2(*(__half2*)&(v).x); \
        float2 f1 = __half22float2(*(__half2*)&(v).y); \
        float2 f2 = __half22float2(*(__half2*)&(v).z); \
        float2 f3 = __half22float2(*(__half2*)&(v).w); \
        a0 += f0.x; a1 += f0.y; a2 += f1.x; a3 += f1.y; \
        a4 += f2.x; a5 += f2.y; a6 += f3.x; a7 += f3.y; }
        const int start = row_ptr[n];
        const int end = row_ptr[n + 1];
        for (int e0 = start; e0 < end; e0 += 16) {
            int mye = e0 + lane16;
            int s = (mye < end) ? col[mye] : -1;
            int jmax = end - e0; if (jmax > 16) jmax = 16;
            int j = 0;
            for (; j + 3 < jmax; j += 4) {
                int s0 = __shfl(s, j, 16),     s1 = __shfl(s, j + 1, 16);
                int s2 = __shfl(s, j + 2, 16), s3 = __shfl(s, j + 3, 16);
                uint4 v0 = *(const uint4*)&Pin[(size_t)s0 * FEAT + f8];
                uint4 v1 = *(const uint4*)&Pin[(size_t)s1 * FEAT + f8];
                uint4 v2 = *(const uint4*)&Pin[(size_t)s2 * FEAT + f8];
                uint4 v3 = *(const uint4*)&Pin[(size_t)s3 * FEAT + f8];
                ACC8(v0); ACC8(v1); ACC8(v2); ACC8(v3);
            }
            for (; j < jmax; ++j) {
                int s0 = __shfl(s, j, 16);
                uint4 v0 = *(const uint4*)&Pin[(size_t)s0 * FEAT + f8];
                ACC8(v0);
            }
        }
#undef ACC8
        const float4 b0 = *(const float4*)&aggBias[f8];
        const float4 b1 = *(const float4*)&aggBias[f8 + 4];
        a0 = fmaxf(a0 * di + b0.x, 0.f); a1 = fmaxf(a1 * di + b0.y, 0.f);
        a2 = fmaxf(a2 * di + b0.z, 0.f); a3 = fmaxf(a3 * di + b0.w, 0.f);
        a4 = fmaxf(a4 * di + b1.x, 0.f); a5 = fmaxf(a5 * di + b1.y, 0.f);
        a6 = fmaxf(a6 * di + b1.z, 0.f); a7 = fmaxf(a7 * di + b1.w, 0.f);
    }

    // write h row into swizzled LDS tile (zeros for n >= N)
    {
        f16x8 hv;
        hv[0] = (f16)a0; hv[1] = (f16)a1; hv[2] = (f16)a2; hv[3] = (f16)a3;
        hv[4] = (f16)a4; hv[5] = (f16)a5; hv[6] = (f16)a6; hv[7] = (f16)a7;
        *(f16x8*)&tile[grp * 128 + ((lane16 * 8) ^ ((grp & 15) << 3))] = hv;
    }
    __syncthreads();

    // Phase 2: 4 waves x 2 n-blocks; A-frags from swizzled tile, B-frags from global
    const int lane = threadIdx.x & 63;
    const int wid = threadIdx.x >> 6;
    const int trow = lane & 15;
    f16x8 af[4];
#pragma unroll
    for (int kk = 0; kk < 4; ++kk)
        af[kk] = *(const f16x8*)&tile[trow * 128 +
                                      ((kk * 32 + (lane >> 4) * 8) ^ ((trow & 15) << 3))];
#pragma unroll
    for (int nb2 = 0; nb2 < 2; ++nb2) {
        const int nb = wid * 2 + nb2;
        f32x4 acc;
        acc[0] = 0.f; acc[1] = 0.f; acc[2] = 0.f; acc[3] = 0.f;
#pragma unroll
        for (int kk = 0; kk < 4; ++kk) {
            f16x8 b = *(const f16x8*)&Wf[((kk * 8 + nb) * 64 + lane) * 8];
            acc = __builtin_amdgcn_mfma_f32_16x16x32_f16(af[kk], b, acc, 0, 0, 0);
        }
        const int c = nb * 16 + (lane & 15);
#pragma unroll
        for (int r = 0; r < 4; ++r) {
            int row = row0 + (lane >> 4) * 4 + r;
            if (row < N) {
                float v = acc[r];
                if (Yh) {
                    Yh[(size_t)row * FEAT + c] = f2h(v * dinv[row]);
                } else {
                    Yf[(size_t)row * FEAT + c] = v + headBias[c];
                }
            }
        }
    }
}

extern "C" void kernel_launch(void* const* d_in, const int* in_sizes, int n_in,
                              void* d_out, int out_size, void* d_ws, size_t ws_size,
                              hipStream_t stream) {
    const float* x  = (const float*)d_in[0];
    const int*   ei = (const int*)d_in[1];
    const float* W1 = (const float*)d_in[2];
    const float* b1 = (const float*)d_in[3];
    const float* W2 = (const float*)d_in[4];
    const float* b2 = (const float*)d_in[5];
    const float* Wl = (const float*)d_in[6];
    const float* bl = (const float*)d_in[7];
    float* out = (float*)d_out;

    const int N = in_sizes[0] / FEAT;      // 100000
    const long long E = in_sizes[1] / 2;   // 3200000
    const int* src = ei;
    const int* dst = ei + E;

    const int nbuck = (N + NPB - 1) >> NPB_SHIFT;    // 196
    const int nchunks = (int)((E + EPB - 1) / EPB);  // 782
    const int nblk = ((nchunks + 7) / 8) * 8;        // 784

    // workspace layout (~68 MB)
    u16*   PbA     = (u16*)d_ws;                       // N*128 fp16 (aliases ebuf)
    u16*   PbB     = PbA + (long long)N * FEAT;        // N*128 fp16
    float* dinv    = (float*)(PbB + (long long)N * FEAT);
    int*   row_ptr = (int*)(dinv + N);                 // N+1
    int*   btot    = row_ptr + N + 1;                  // 256
    int*   bbase   = btot + 256;                       // 256
    int*   cmat    = bbase + 256;                      // nbuck*nblk
    u16*   Wf1     = (u16*)(cmat + (long long)nbuck * nblk);  // 16384
    u16*   Wf2     = Wf1 + 16384;
    u16*   Wfl     = Wf2 + 16384;
    int*   col     = (int*)(Wfl + 16384);              // E
    u32*   ebuf    = (u32*)PbA;                        // E u32 (12.8MB, in PbA)

    // ---- bucket radix: sort edges by dst bucket (packed u32) ----
    radix_count_kernel<<<nblk, 256, 0, stream>>>(dst, cmat, E, nbuck, nblk);
    radix_btot_kernel<<<nbuck, 256, 0, stream>>>(cmat, btot, nblk);
    radix_bscan_kernel<<<1, 256, 0, stream>>>(btot, bbase, nbuck);
    radix_colscan_kernel<<<nbuck, 256, 0, stream>>>(cmat, bbase, nblk);
    radix_scatter_kernel<<<nblk, 256, 0, stream>>>(src, dst, cmat, ebuf, E, nbuck, nblk);

    // ---- per-bucket finisher: row_ptr, dinv, col (consumes ebuf) ----
    bucket_finish_kernel<<<nbuck, 1024, 0, stream>>>(ebuf, bbase, btot, col, row_ptr,
                                                     dinv, N, nbuck, E);

    // ---- weight prepack ----
    prepack_w_kernel<<<3, 256, 0, stream>>>(W1, W2, Wl, Wf1, Wf2, Wfl);

    const int gemmGrid = ((N + 31) / 32 + 3) / 4;
    const int fusedGrid = (N + 15) / 16;

    // ---- layer 1 projection: P1' = dinv * (x @ W1) (writes PbA; ebuf consumed) ----
    mfma_gemm1_kernel<<<gemmGrid, 256, 0, stream>>>(x, Wf1, dinv, PbA, N);

    // ---- h1 agg + layer-2 projection: P2' = dinv * (relu(agg)@W2) ----
    gather_gemm_kernel<<<fusedGrid, 256, 0, stream>>>(row_ptr, col, dinv, PbA, b1,
                                                      Wf2, nullptr, PbB, nullptr, N);

    // ---- h2 agg + head: out = relu(agg) @ Wl + bl ----
    gather_gemm_kernel<<<fusedGrid, 256, 0, stream>>>(row_ptr, col, dinv, PbB, b2,
                                                      Wfl, bl, nullptr, out, N);
}